// Round 9
// baseline (146.571 us; speedup 1.0000x reference)
//
#include <hip/hip_runtime.h>
#include <cstddef>
#include <cstdint>

typedef float  f32x4  __attribute__((ext_vector_type(4)));
typedef float  f32x16 __attribute__((ext_vector_type(16)));
typedef __bf16 bf16x8 __attribute__((ext_vector_type(8)));
typedef unsigned short ushort_t;
typedef unsigned int __attribute__((address_space(1))) u32_g;
typedef unsigned int __attribute__((address_space(3))) u32_l;

#define S_LEN  2048
#define DMODEL 1024
#define NH     16
#define QKV_LD 3072   // fused QKV row stride (Q|K|V)
#define LOG2E  1.4426950408889634f

static __device__ __forceinline__ ushort_t f2bf(float f) {
    union { float f; unsigned u; } v; v.f = f;
    unsigned r = (v.u + 0x7FFFu + ((v.u >> 16) & 1u)) >> 16;
    return (ushort_t)r;
}
static __device__ __forceinline__ float bf2f(ushort_t b) {
    union { unsigned u; float f; } v; v.u = ((unsigned)b) << 16;
    return v.f;
}
// pack two f32 -> 2xbf16 dword (compiler emits v_cvt_pk_bf16_f32)
static __device__ __forceinline__ unsigned cvtpk(float a, float b) {
    union { __bf16 h[2]; unsigned u; } t;
    t.h[0] = (__bf16)a; t.h[1] = (__bf16)b;
    return t.u;
}
// 2^x via v_exp_f32 (inputs pre-scaled by log2e)
static __device__ __forceinline__ float fexp2(float x) {
#if __has_builtin(__builtin_amdgcn_exp2f)
    return __builtin_amdgcn_exp2f(x);
#else
    return __expf(x * 0.6931471805599453f);
#endif
}
// async 16B global->LDS; lds dst = wave-uniform base + lane*16
static __device__ __forceinline__ void load_lds16(const void* g, void* l) {
    __builtin_amdgcn_global_load_lds((const u32_g*)g, (u32_l*)l, 16, 0, 0);
}
static __device__ __forceinline__ int rel_bucket(int rp) {
    int arp = rp < 0 ? -rp : rp;
    int bucket;
    if (arp < 8) bucket = arp;
    else { int lg = 33 - __clz(arp * arp); bucket = lg < 15 ? lg : 15; }
    return rp > 0 ? bucket + 16 : bucket;
}

// ---------------- cast X (fp32 -> bf16), elementwise ----------------
__global__ __launch_bounds__(256) void cast_x(const float* __restrict__ X,
                                              ushort_t* __restrict__ Xb, int n4) {
    int i = blockIdx.x * 256 + threadIdx.x;
    if (i < n4) {
        float4 v = ((const float4*)X)[i];
        ushort4 o = make_ushort4(f2bf(v.x), f2bf(v.y), f2bf(v.z), f2bf(v.w));
        ((ushort4*)Xb)[i] = o;
    }
}

// ------------- weight transpose+cast: W[k][n] fp32 -> W^T[n][k] bf16 -------------
__global__ __launch_bounds__(256) void wcast(
    const float* __restrict__ Wq, const float* __restrict__ Wk,
    const float* __restrict__ Wv, const float* __restrict__ Wo,
    ushort_t* __restrict__ Wt, ushort_t* __restrict__ Wot)
{
    __shared__ float T[64][68];
    const int z = blockIdx.z;
    const float* W = (z == 0) ? Wq : (z == 1) ? Wk : (z == 2) ? Wv : Wo;
    ushort_t* Out = (z == 3) ? Wot : (Wt + (size_t)z * 1024 * 1024);
    const int k0 = blockIdx.y * 64, n0 = blockIdx.x * 64;
    const int t = threadIdx.x;
    #pragma unroll
    for (int i = 0; i < 4; i++) {
        int g = i * 256 + t; int kl = g >> 4, ng = g & 15;
        float4 v = *(const float4*)&W[(size_t)(k0 + kl) * 1024 + n0 + ng * 4];
        *(float4*)&T[kl][ng * 4] = v;
    }
    __syncthreads();
    #pragma unroll
    for (int i = 0; i < 2; i++) {
        int g = i * 256 + t; int nl = g >> 3, kg = g & 7;
        alignas(16) ushort_t pk[8];
        #pragma unroll
        for (int j = 0; j < 8; j++) pk[j] = f2bf(T[kg * 8 + j][nl]);
        *(uint4*)&Out[(size_t)(n0 + nl) * 1024 + k0 + kg * 8] = *(uint4*)pk;
    }
}

// -------- bf16 MFMA GEMM 128x64 tile (QKV projection), dbuf staging --------
// 768 blocks (3/CU exact). Q cols pre-scaled by log2e (exp2 softmax).
// V-section tiles (n0>=2048) are written TRANSPOSED into Vt[h][d][s]
// directly from the accumulator, replacing a separate vt_trans kernel.
__global__ __launch_bounds__(256) void gemm_bf16(
    const ushort_t* __restrict__ A, const ushort_t* __restrict__ B,
    ushort_t* __restrict__ Cout, ushort_t* __restrict__ Vt,
    int M, int N, int K)
{
    __shared__ ushort_t As[2][128 * 64];
    __shared__ ushort_t Bs[2][64 * 64];
    const int tid = threadIdx.x;
    const int w = tid >> 6, lane = tid & 63, quad = lane >> 4, cid = lane & 15;
    const int wm = w >> 1, wn = w & 1;
    const int m0 = blockIdx.y * 128, n0 = blockIdx.x * 64;

    auto stage = [&](int b, int k0) {
        #pragma unroll
        for (int i = 0; i < 4; i++) {
            int g = i * 256 + tid; int r = g >> 3, kg = g & 7;
            int dg = kg ^ (r & 7);
            load_lds16(A + (size_t)(m0 + r) * K + k0 + dg * 8, &As[b][(i * 256 + w * 64) * 8]);
        }
        #pragma unroll
        for (int i = 0; i < 2; i++) {
            int g = i * 256 + tid; int r = g >> 3, kg = g & 7;
            int dg = kg ^ (r & 7);
            load_lds16(B + (size_t)(n0 + r) * K + k0 + dg * 8, &Bs[b][(i * 256 + w * 64) * 8]);
        }
    };

    f32x4 acc[4][2] = {};
    stage(0, 0);
    int cur = 0;
    #pragma unroll 1
    for (int k0 = 0; k0 < K; k0 += 64) {
        if (k0 + 64 < K) {
            stage(cur ^ 1, k0 + 64);
            asm volatile("s_waitcnt vmcnt(6)" ::: "memory");
        } else {
            asm volatile("s_waitcnt vmcnt(0)" ::: "memory");
        }
        __builtin_amdgcn_s_barrier();
        __builtin_amdgcn_sched_barrier(0);
        #pragma unroll
        for (int kk = 0; kk < 2; kk++) {
            bf16x8 af[4], bf[2];
            #pragma unroll
            for (int t = 0; t < 4; t++) {
                int m = wm * 64 + t * 16 + cid;
                af[t] = *(const bf16x8*)&As[cur][m * 64 + (((kk * 4 + quad) ^ (m & 7)) * 8)];
            }
            #pragma unroll
            for (int t = 0; t < 2; t++) {
                int n = wn * 32 + t * 16 + cid;
                bf[t] = *(const bf16x8*)&Bs[cur][n * 64 + (((kk * 4 + quad) ^ (n & 7)) * 8)];
            }
            #pragma unroll
            for (int i = 0; i < 4; i++)
                #pragma unroll
                for (int j = 0; j < 2; j++)
                    acc[i][j] = __builtin_amdgcn_mfma_f32_16x16x32_bf16(af[i], bf[j], acc[i][j], 0, 0, 0);
        }
        __builtin_amdgcn_s_barrier();
        cur ^= 1;
    }
    if (n0 >= 2048) {
        // V tile: write transposed into Vt[h*64+d][s]; rows (s) contiguous per lane
        const int hh = (n0 - 2048) >> 6;
        #pragma unroll
        for (int i = 0; i < 4; i++)
            #pragma unroll
            for (int j = 0; j < 2; j++) {
                int col = n0 + wn * 32 + j * 16 + cid;
                int dl = col & 63;
                int row0 = m0 + wm * 64 + i * 16 + quad * 4;
                alignas(8) ushort_t pk[4];
                #pragma unroll
                for (int r = 0; r < 4; r++) pk[r] = f2bf(acc[i][j][r]);
                *(uint2*)&Vt[(size_t)(hh * 64 + dl) * S_LEN + row0] = *(uint2*)pk;
            }
    } else {
        const float qs = (n0 < 1024) ? LOG2E : 1.0f;   // pre-scale Q for exp2 softmax
        #pragma unroll
        for (int i = 0; i < 4; i++)
            #pragma unroll
            for (int j = 0; j < 2; j++)
                #pragma unroll
                for (int r = 0; r < 4; r++) {
                    int row = m0 + wm * 64 + i * 16 + quad * 4 + r;
                    int col = n0 + wn * 32 + j * 16 + cid;
                    Cout[(size_t)row * N + col] = f2bf(acc[i][j][r] * qs);
                }
    }
}

// ------ bf16 MFMA GEMM 64x64, fp32 out (output projection), double-buffered ------
__global__ __launch_bounds__(256) void gemm64_f32(
    const ushort_t* __restrict__ A, const ushort_t* __restrict__ B,
    float* __restrict__ Cout, int M, int N, int K)
{
    __shared__ ushort_t As[2][64 * 64];
    __shared__ ushort_t Bs[2][64 * 64];
    const int tid = threadIdx.x;
    const int w = tid >> 6, lane = tid & 63, quad = lane >> 4, cid = lane & 15;
    const int wm = w >> 1, wn = w & 1;
    const int m0 = blockIdx.y * 64, n0 = blockIdx.x * 64;

    auto stage = [&](int b, int k0) {
        #pragma unroll
        for (int i = 0; i < 2; i++) {
            int g = i * 256 + tid; int r = g >> 3, kg = g & 7;
            int dg = kg ^ (r & 7);
            load_lds16(A + (size_t)(m0 + r) * K + k0 + dg * 8, &As[b][(i * 256 + w * 64) * 8]);
            load_lds16(B + (size_t)(n0 + r) * K + k0 + dg * 8, &Bs[b][(i * 256 + w * 64) * 8]);
        }
    };

    f32x4 acc[2][2] = {};
    stage(0, 0);
    int cur = 0;
    #pragma unroll 1
    for (int k0 = 0; k0 < K; k0 += 64) {
        if (k0 + 64 < K) {
            stage(cur ^ 1, k0 + 64);
            asm volatile("s_waitcnt vmcnt(4)" ::: "memory");
        } else {
            asm volatile("s_waitcnt vmcnt(0)" ::: "memory");
        }
        __builtin_amdgcn_s_barrier();
        __builtin_amdgcn_sched_barrier(0);
        #pragma unroll
        for (int kk = 0; kk < 2; kk++) {
            bf16x8 af[2], bf[2];
            #pragma unroll
            for (int t = 0; t < 2; t++) {
                int m = wm * 32 + t * 16 + cid;
                af[t] = *(const bf16x8*)&As[cur][m * 64 + (((kk * 4 + quad) ^ (m & 7)) * 8)];
                int n = wn * 32 + t * 16 + cid;
                bf[t] = *(const bf16x8*)&Bs[cur][n * 64 + (((kk * 4 + quad) ^ (n & 7)) * 8)];
            }
            #pragma unroll
            for (int i = 0; i < 2; i++)
                #pragma unroll
                for (int j = 0; j < 2; j++)
                    acc[i][j] = __builtin_amdgcn_mfma_f32_16x16x32_bf16(af[i], bf[j], acc[i][j], 0, 0, 0);
        }
        __builtin_amdgcn_s_barrier();
        cur ^= 1;
    }
    #pragma unroll
    for (int i = 0; i < 2; i++)
        #pragma unroll
        for (int j = 0; j < 2; j++)
            #pragma unroll
            for (int r = 0; r < 4; r++) {
                int row = m0 + wm * 32 + i * 16 + quad * 4 + r;
                int col = n0 + wn * 32 + j * 16 + cid;
                Cout[(size_t)row * N + col] = acc[i][j][r];
            }
}

// ----- MFMA flash attention, 32x32x16, fixed-max (m=0), NO split-K, 8-wave -----
// Grid (16,16) XCD-swizzled = 256 blocks x 512 threads (1/CU). Full 2048-key
// loop per block -> writes NORMALIZED Ctx directly (attn_reduce eliminated).
// KVBLK=128 DOUBLE-buffered (2 bufs x 2 subs x K,V = 64 KB) with counted
// vmcnt(4): prefetch flies across the barrier while current buffer computes
// (the stage drain that r7 proved is the remaining attn cost).
// 8 waves = 4 q-subtiles (wq) x 2 key-halves (wk); in-register softmax.
__global__ __launch_bounds__(512) void attn_mfma(
    const ushort_t* __restrict__ QKV, const ushort_t* __restrict__ Vt,
    const float* __restrict__ rel_bias, ushort_t* __restrict__ Ctx)
{
    __shared__ float    tab[2176];             // bias*log2e, rp in [-q0-127, 2047-q0]
    __shared__ ushort_t KV[2][2][2][64 * 64];  // [buf][sub][K/V], 64 KB
    __shared__ float    Lsh[64];

    const int tid = threadIdx.x;
    const int w = tid >> 6, lane = tid & 63;
    const int cid32 = lane & 31, hi = lane >> 5;
    const int wq = w >> 1, wk = w & 1;   // wq 0..3, wk 0..1

    // XCD-aware bijective swizzle (256 blocks, 8 XCDs, 32 per XCD = 2 heads)
    const int lin  = blockIdx.x + (blockIdx.y << 4);
    const int wgid = (lin & 7) * 32 + (lin >> 3);
    const int qt = wgid & 15, h = (wgid >> 4) & 15;
    const int q0 = qt * 128;

    // bias table for rp = k - q in [-q0 - 127, 2047 - q0]
    const int rpmin = -q0 - 127;
    for (int idx = tid; idx < 2175; idx += 512)
        tab[idx] = rel_bias[rel_bucket(rpmin + idx) * NH + h] * LOG2E;

    // Q fragments (B operand of swapped QK^T); Q pre-scaled by log2e in gemm
    const int qg = q0 + wq * 32 + cid32;
    bf16x8 qf[4];
    #pragma unroll
    for (int s = 0; s < 4; s++)
        qf[s] = *(const bf16x8*)&QKV[(size_t)qg * QKV_LD + h * 64 + s * 16 + hi * 8];

    bf16x8 vones;
    {
        union { ushort_t u; __bf16 b; } c; c.u = 0x3F80;  // bf16 1.0
        #pragma unroll
        for (int i = 0; i < 8; i++) vones[i] = c.b;
    }

    f32x16 Oacc[2] = {};   // [dt]: rows q=rowmap(r), col d = dt*32+cid32
    f32x16 Lacc = {};      // rows q=rowmap(r), all cols identical

    const float* tb0 = &tab[wk * 32 + 4 * hi + 127 - wq * 32 - cid32];
    const int krow = wk * 32 + cid32;    // K row this lane reads (A operand)
    const int kxor = krow & 7;

    // per-thread static staging slot: row = tid>>3 (0..63), kg = tid&7
    const int srow = tid >> 3, skg = tid & 7;
    const int sdg = skg ^ (srow & 7);

    auto stage = [&](int buf, int k0) {   // stages keys [k0, k0+128)
        #pragma unroll
        for (int sub = 0; sub < 2; sub++) {
            load_lds16(QKV + (size_t)(k0 + sub * 64 + srow) * QKV_LD + 1024 + h * 64 + sdg * 8,
                       &KV[buf][sub][0][w * 512]);
            load_lds16(Vt + (size_t)(h * 64 + srow) * S_LEN + k0 + sub * 64 + sdg * 8,
                       &KV[buf][sub][1][w * 512]);
        }
    };

    __syncthreads();   // tab ready (also covers qf ordering)
    stage(0, 0);

    int cur = 0;
    #pragma unroll 1
    for (int t = 0; t < 16; ++t) {
        const int k0 = t * 128;
        if (t < 15) {
            stage(cur ^ 1, k0 + 128);                       // prefetch next 128 keys
            asm volatile("s_waitcnt vmcnt(4)" ::: "memory"); // current buf landed
        } else {
            asm volatile("s_waitcnt vmcnt(0)" ::: "memory");
        }
        __builtin_amdgcn_s_barrier();
        __builtin_amdgcn_sched_barrier(0);

        #pragma unroll
        for (int sub = 0; sub < 2; sub++) {
            // S^T accumulator init = bias (MFMA C-operand carries it through)
            const float* tb = tb0 + k0 + sub * 64;
            f32x16 ST;
            #pragma unroll
            for (int r = 0; r < 16; r++)
                ST[r] = tb[(r & 3) + 8 * (r >> 2)];

            // S^T = K @ Q^T + bias: lane holds col q=cid32, rows key=rowmap(r)+4*hi
            __builtin_amdgcn_s_setprio(1);
            #pragma unroll
            for (int s = 0; s < 4; s++) {
                bf16x8 kf = *(const bf16x8*)&KV[cur][sub][0][krow * 64 + (((s * 2 + hi) ^ kxor) * 8)];
                ST = __builtin_amdgcn_mfma_f32_32x32x16_bf16(kf, qf[s], ST, 0, 0, 0);
            }
            __builtin_amdgcn_s_setprio(0);

            // p = 2^(S + bias)  (both pre-scaled by log2e); pack key-pairs to bf16
            unsigned u[4][2];
            #pragma unroll
            for (int m = 0; m < 4; m++) {
                u[m][0] = cvtpk(fexp2(ST[4 * m + 0]), fexp2(ST[4 * m + 1]));
                u[m][1] = cvtpk(fexp2(ST[4 * m + 2]), fexp2(ST[4 * m + 3]));
            }

            // per 16-key step: assemble PV A-fragment in-register (2 permlane32_swap)
            #pragma unroll
            for (int s2 = 0; s2 < 2; s2++) {
                unsigned x0 = u[2 * s2][0], x1 = u[2 * s2][1];
                unsigned y0 = u[2 * s2 + 1][0], y1 = u[2 * s2 + 1][1];
                asm("v_permlane32_swap_b32 %0, %1" : "+v"(x0), "+v"(y0));
                asm("v_permlane32_swap_b32 %0, %1" : "+v"(x1), "+v"(y1));
                union { unsigned d[4]; bf16x8 v; } pa;
                pa.d[0] = x0; pa.d[1] = x1; pa.d[2] = y0; pa.d[3] = y1;

                __builtin_amdgcn_s_setprio(1);
                // l += P @ 1
                Lacc = __builtin_amdgcn_mfma_f32_32x32x16_bf16(pa.v, vones, Lacc, 0, 0, 0);
                // O += P @ V
                #pragma unroll
                for (int dt = 0; dt < 2; dt++) {
                    int drow = dt * 32 + cid32;
                    bf16x8 vf = *(const bf16x8*)&KV[cur][sub][1][drow * 64 +
                                    (((wk * 4 + s2 * 2 + hi) ^ (drow & 7)) * 8)];
                    Oacc[dt] = __builtin_amdgcn_mfma_f32_32x32x16_bf16(pa.v, vf, Oacc[dt], 0, 0, 0);
                }
                __builtin_amdgcn_s_setprio(0);
            }
        }
        __builtin_amdgcn_s_barrier();   // reads of buf[cur] done before overwrite
        cur ^= 1;
    }

    // ---- combine key-halves (wk) via LDS, normalize, write Ctx directly ----
    __syncthreads();
    float* Osh = (float*)&KV[0][0][0][0];   // 16 KB scratch, KV dead now
    #pragma unroll 1
    for (int p = 0; p < 2; p++) {
        if (wk == 0 && (wq >> 1) == p) {
            #pragma unroll
            for (int dt = 0; dt < 2; dt++)
                #pragma unroll
                for (int r = 0; r < 16; r++) {
                    int rloc = (r & 3) + 8 * (r >> 2) + 4 * hi;
                    Osh[((wq & 1) * 32 + rloc) * 64 + dt * 32 + cid32] = Oacc[dt][r];
                }
            if (cid32 == 0)
                #pragma unroll
                for (int r = 0; r < 16; r++)
                    Lsh[(wq & 1) * 32 + (r & 3) + 8 * (r >> 2) + 4 * hi] = Lacc[r];
        }
        __syncthreads();
        if (wk == 1 && (wq >> 1) == p) {
            #pragma unroll
            for (int r = 0; r < 16; r++) {
                int rloc = (r & 3) + 8 * (r >> 2) + 4 * hi;
                int row = q0 + wq * 32 + rloc;
                float inv = 1.f / (Lacc[r] + Lsh[(wq & 1) * 32 + rloc]);
                #pragma unroll
                for (int dt = 0; dt < 2; dt++) {
                    float o = (Oacc[dt][r]
                             + Osh[((wq & 1) * 32 + rloc) * 64 + dt * 32 + cid32]) * inv;
                    Ctx[(size_t)row * DMODEL + h * 64 + dt * 32 + cid32] = f2bf(o);
                }
            }
        }
        __syncthreads();
    }
}

// ---------------- launch ----------------
extern "C" void kernel_launch(void* const* d_in, const int* in_sizes, int n_in,
                              void* d_out, int out_size, void* d_ws, size_t ws_size,
                              hipStream_t stream) {
    const float* X  = (const float*)d_in[0];
    const float* Wq = (const float*)d_in[1];
    const float* Wk = (const float*)d_in[2];
    const float* Wv = (const float*)d_in[3];
    const float* Wo = (const float*)d_in[4];
    const float* rb = (const float*)d_in[5];
    float* out = (float*)d_out;

    ushort_t* ws = (ushort_t*)d_ws;
    const size_t M1 = 1024 * 1024;
    // Region timeline (ushort units, 14M total = 28 MB):
    //  0..2M   Xb (bf16 X)        -> dead after QKV gemm -> Ctx (attn output)
    //  2..5M   Wt                 -> dead after QKV gemm
    //  5..6M   Wot                (live until final gemm)
    //  6..12M  QKV                (live through attn)
    // 12..14M  Vt                 (live through attn)
    ushort_t* Xb    = ws;
    ushort_t* Wt    = ws + 2 * M1;
    ushort_t* Wot   = ws + 5 * M1;
    ushort_t* QKV   = ws + 6 * M1;
    ushort_t* Vt    = ws + 12 * M1;
    ushort_t* Ctx   = ws;                       // 2M ushort, over dead Xb

    cast_x<<<dim3((S_LEN * DMODEL / 4 + 255) / 256), 256, 0, stream>>>(X, Xb, S_LEN * DMODEL / 4);
    wcast<<<dim3(16, 16, 4), 256, 0, stream>>>(Wq, Wk, Wv, Wo, Wt, Wot);
    gemm_bf16<<<dim3(48, 16), 256, 0, stream>>>(Xb, Wt, QKV, Vt, S_LEN, 3072, DMODEL);
    attn_mfma<<<dim3(16, 16), 512, 0, stream>>>(QKV, Vt, rb, Ctx);
    gemm64_f32<<<dim3(16, 32), 256, 0, stream>>>(Ctx, Wot, out, S_LEN, DMODEL, DMODEL);
}

// Round 10
// 141.207 us; speedup vs baseline: 1.0380x; 1.0380x over previous
//
#include <hip/hip_runtime.h>
#include <cstddef>
#include <cstdint>

typedef float  f32x4  __attribute__((ext_vector_type(4)));
typedef float  f32x16 __attribute__((ext_vector_type(16)));
typedef __bf16 bf16x8 __attribute__((ext_vector_type(8)));
typedef unsigned short ushort_t;
typedef unsigned int __attribute__((address_space(1))) u32_g;
typedef unsigned int __attribute__((address_space(3))) u32_l;

#define S_LEN  2048
#define DMODEL 1024
#define NH     16
#define QKV_LD 3072   // fused QKV row stride (Q|K|V)
#define LOG2E  1.4426950408889634f

static __device__ __forceinline__ ushort_t f2bf(float f) {
    union { float f; unsigned u; } v; v.f = f;
    unsigned r = (v.u + 0x7FFFu + ((v.u >> 16) & 1u)) >> 16;
    return (ushort_t)r;
}
static __device__ __forceinline__ float bf2f(ushort_t b) {
    union { unsigned u; float f; } v; v.u = ((unsigned)b) << 16;
    return v.f;
}
// pack two f32 -> 2xbf16 dword (compiler emits v_cvt_pk_bf16_f32)
static __device__ __forceinline__ unsigned cvtpk(float a, float b) {
    union { __bf16 h[2]; unsigned u; } t;
    t.h[0] = (__bf16)a; t.h[1] = (__bf16)b;
    return t.u;
}
// 2^x via v_exp_f32 (inputs pre-scaled by log2e)
static __device__ __forceinline__ float fexp2(float x) {
#if __has_builtin(__builtin_amdgcn_exp2f)
    return __builtin_amdgcn_exp2f(x);
#else
    return __expf(x * 0.6931471805599453f);
#endif
}
// async 16B global->LDS; lds dst = wave-uniform base + lane*16
static __device__ __forceinline__ void load_lds16(const void* g, void* l) {
    __builtin_amdgcn_global_load_lds((const u32_g*)g, (u32_l*)l, 16, 0, 0);
}
static __device__ __forceinline__ int rel_bucket(int rp) {
    int arp = rp < 0 ? -rp : rp;
    int bucket;
    if (arp < 8) bucket = arp;
    else { int lg = 33 - __clz(arp * arp); bucket = lg < 15 ? lg : 15; }
    return rp > 0 ? bucket + 16 : bucket;
}

// ---- weight transpose+cast (z<4) + X fp32->bf16 cast (z==4), one kernel ----
__global__ __launch_bounds__(256) void wcast(
    const float* __restrict__ X, ushort_t* __restrict__ Xb,
    const float* __restrict__ Wq, const float* __restrict__ Wk,
    const float* __restrict__ Wv, const float* __restrict__ Wo,
    ushort_t* __restrict__ Wt, ushort_t* __restrict__ Wot)
{
    const int t = threadIdx.x;
    if (blockIdx.z == 4) {
        // cast X: 2M floats = 512K float4; 256 blocks x 2048 float4
        int base = (blockIdx.y * 16 + blockIdx.x) * 2048;
        #pragma unroll
        for (int i = 0; i < 8; i++) {
            int idx = base + i * 256 + t;
            float4 v = ((const float4*)X)[idx];
            ushort4 o = make_ushort4(f2bf(v.x), f2bf(v.y), f2bf(v.z), f2bf(v.w));
            ((ushort4*)Xb)[idx] = o;
        }
        return;
    }
    __shared__ float T[64][68];
    const int z = blockIdx.z;
    const float* W = (z == 0) ? Wq : (z == 1) ? Wk : (z == 2) ? Wv : Wo;
    ushort_t* Out = (z == 3) ? Wot : (Wt + (size_t)z * 1024 * 1024);
    const int k0 = blockIdx.y * 64, n0 = blockIdx.x * 64;
    #pragma unroll
    for (int i = 0; i < 4; i++) {
        int g = i * 256 + t; int kl = g >> 4, ng = g & 15;
        float4 v = *(const float4*)&W[(size_t)(k0 + kl) * 1024 + n0 + ng * 4];
        *(float4*)&T[kl][ng * 4] = v;
    }
    __syncthreads();
    #pragma unroll
    for (int i = 0; i < 2; i++) {
        int g = i * 256 + t; int nl = g >> 3, kg = g & 7;
        alignas(16) ushort_t pk[8];
        #pragma unroll
        for (int j = 0; j < 8; j++) pk[j] = f2bf(T[kg * 8 + j][nl]);
        *(uint4*)&Out[(size_t)(n0 + nl) * 1024 + k0 + kg * 8] = *(uint4*)pk;
    }
}

// -------- bf16 MFMA GEMM 128x64 tile (QKV projection), dbuf staging --------
// 768 blocks (3/CU exact). Q cols pre-scaled by log2e (exp2 softmax).
// V-section tiles (n0>=2048) are written TRANSPOSED into Vt[h][d][s]
// directly from the accumulator, replacing a separate vt_trans kernel.
__global__ __launch_bounds__(256) void gemm_bf16(
    const ushort_t* __restrict__ A, const ushort_t* __restrict__ B,
    ushort_t* __restrict__ Cout, ushort_t* __restrict__ Vt,
    int M, int N, int K)
{
    __shared__ ushort_t As[2][128 * 64];
    __shared__ ushort_t Bs[2][64 * 64];
    const int tid = threadIdx.x;
    const int w = tid >> 6, lane = tid & 63, quad = lane >> 4, cid = lane & 15;
    const int wm = w >> 1, wn = w & 1;
    const int m0 = blockIdx.y * 128, n0 = blockIdx.x * 64;

    auto stage = [&](int b, int k0) {
        #pragma unroll
        for (int i = 0; i < 4; i++) {
            int g = i * 256 + tid; int r = g >> 3, kg = g & 7;
            int dg = kg ^ (r & 7);
            load_lds16(A + (size_t)(m0 + r) * K + k0 + dg * 8, &As[b][(i * 256 + w * 64) * 8]);
        }
        #pragma unroll
        for (int i = 0; i < 2; i++) {
            int g = i * 256 + tid; int r = g >> 3, kg = g & 7;
            int dg = kg ^ (r & 7);
            load_lds16(B + (size_t)(n0 + r) * K + k0 + dg * 8, &Bs[b][(i * 256 + w * 64) * 8]);
        }
    };

    f32x4 acc[4][2] = {};
    stage(0, 0);
    int cur = 0;
    #pragma unroll 1
    for (int k0 = 0; k0 < K; k0 += 64) {
        if (k0 + 64 < K) {
            stage(cur ^ 1, k0 + 64);
            asm volatile("s_waitcnt vmcnt(6)" ::: "memory");
        } else {
            asm volatile("s_waitcnt vmcnt(0)" ::: "memory");
        }
        __builtin_amdgcn_s_barrier();
        __builtin_amdgcn_sched_barrier(0);
        #pragma unroll
        for (int kk = 0; kk < 2; kk++) {
            bf16x8 af[4], bf[2];
            #pragma unroll
            for (int t = 0; t < 4; t++) {
                int m = wm * 64 + t * 16 + cid;
                af[t] = *(const bf16x8*)&As[cur][m * 64 + (((kk * 4 + quad) ^ (m & 7)) * 8)];
            }
            #pragma unroll
            for (int t = 0; t < 2; t++) {
                int n = wn * 32 + t * 16 + cid;
                bf[t] = *(const bf16x8*)&Bs[cur][n * 64 + (((kk * 4 + quad) ^ (n & 7)) * 8)];
            }
            #pragma unroll
            for (int i = 0; i < 4; i++)
                #pragma unroll
                for (int j = 0; j < 2; j++)
                    acc[i][j] = __builtin_amdgcn_mfma_f32_16x16x32_bf16(af[i], bf[j], acc[i][j], 0, 0, 0);
        }
        __builtin_amdgcn_s_barrier();
        cur ^= 1;
    }
    if (n0 >= 2048) {
        // V tile: write transposed into Vt[h*64+d][s]; rows (s) contiguous per lane
        const int hh = (n0 - 2048) >> 6;
        #pragma unroll
        for (int i = 0; i < 4; i++)
            #pragma unroll
            for (int j = 0; j < 2; j++) {
                int col = n0 + wn * 32 + j * 16 + cid;
                int dl = col & 63;
                int row0 = m0 + wm * 64 + i * 16 + quad * 4;
                alignas(8) ushort_t pk[4];
                #pragma unroll
                for (int r = 0; r < 4; r++) pk[r] = f2bf(acc[i][j][r]);
                *(uint2*)&Vt[(size_t)(hh * 64 + dl) * S_LEN + row0] = *(uint2*)pk;
            }
    } else {
        const float qs = (n0 < 1024) ? LOG2E : 1.0f;   // pre-scale Q for exp2 softmax
        #pragma unroll
        for (int i = 0; i < 4; i++)
            #pragma unroll
            for (int j = 0; j < 2; j++)
                #pragma unroll
                for (int r = 0; r < 4; r++) {
                    int row = m0 + wm * 64 + i * 16 + quad * 4 + r;
                    int col = n0 + wn * 32 + j * 16 + cid;
                    Cout[(size_t)row * N + col] = f2bf(acc[i][j][r] * qs);
                }
    }
}

// ------ bf16 MFMA GEMM 64x64, fp32 out (output projection), double-buffered ------
__global__ __launch_bounds__(256) void gemm64_f32(
    const ushort_t* __restrict__ A, const ushort_t* __restrict__ B,
    float* __restrict__ Cout, int M, int N, int K)
{
    __shared__ ushort_t As[2][64 * 64];
    __shared__ ushort_t Bs[2][64 * 64];
    const int tid = threadIdx.x;
    const int w = tid >> 6, lane = tid & 63, quad = lane >> 4, cid = lane & 15;
    const int wm = w >> 1, wn = w & 1;
    const int m0 = blockIdx.y * 64, n0 = blockIdx.x * 64;

    auto stage = [&](int b, int k0) {
        #pragma unroll
        for (int i = 0; i < 2; i++) {
            int g = i * 256 + tid; int r = g >> 3, kg = g & 7;
            int dg = kg ^ (r & 7);
            load_lds16(A + (size_t)(m0 + r) * K + k0 + dg * 8, &As[b][(i * 256 + w * 64) * 8]);
            load_lds16(B + (size_t)(n0 + r) * K + k0 + dg * 8, &Bs[b][(i * 256 + w * 64) * 8]);
        }
    };

    f32x4 acc[2][2] = {};
    stage(0, 0);
    int cur = 0;
    #pragma unroll 1
    for (int k0 = 0; k0 < K; k0 += 64) {
        if (k0 + 64 < K) {
            stage(cur ^ 1, k0 + 64);
            asm volatile("s_waitcnt vmcnt(4)" ::: "memory");
        } else {
            asm volatile("s_waitcnt vmcnt(0)" ::: "memory");
        }
        __builtin_amdgcn_s_barrier();
        __builtin_amdgcn_sched_barrier(0);
        #pragma unroll
        for (int kk = 0; kk < 2; kk++) {
            bf16x8 af[2], bf[2];
            #pragma unroll
            for (int t = 0; t < 2; t++) {
                int m = wm * 32 + t * 16 + cid;
                af[t] = *(const bf16x8*)&As[cur][m * 64 + (((kk * 4 + quad) ^ (m & 7)) * 8)];
                int n = wn * 32 + t * 16 + cid;
                bf[t] = *(const bf16x8*)&Bs[cur][n * 64 + (((kk * 4 + quad) ^ (n & 7)) * 8)];
            }
            #pragma unroll
            for (int i = 0; i < 2; i++)
                #pragma unroll
                for (int j = 0; j < 2; j++)
                    acc[i][j] = __builtin_amdgcn_mfma_f32_16x16x32_bf16(af[i], bf[j], acc[i][j], 0, 0, 0);
        }
        __builtin_amdgcn_s_barrier();
        cur ^= 1;
    }
    #pragma unroll
    for (int i = 0; i < 2; i++)
        #pragma unroll
        for (int j = 0; j < 2; j++)
            #pragma unroll
            for (int r = 0; r < 4; r++) {
                int row = m0 + wm * 32 + i * 16 + quad * 4 + r;
                int col = n0 + wn * 32 + j * 16 + cid;
                Cout[(size_t)row * N + col] = acc[i][j][r];
            }
}

// ----- MFMA flash attention, 32x32x16, fixed-max (m=0), NO split-K, 8-wave -----
// Grid (32,16) XCD-swizzled = 512 blocks x 512 threads = 2 blocks/CU, 16
// waves/CU (the TLP that r7 proved and r9 lost). q-tile = 64 rows; 8 waves =
// 2 q-halves (wq) x 4 KEY-QUARTERS (wk, 32 keys of the 128-key chunk each).
// KVBLK=128 double-buffered (64 KB) with counted vmcnt(4). Normalized Ctx
// written directly (no reduce kernel). __launch_bounds__(512,4) pins VGPR<=128
// so 4 waves/SIMD is achievable.
__global__ __launch_bounds__(512, 4) void attn_mfma(
    const ushort_t* __restrict__ QKV, const ushort_t* __restrict__ Vt,
    const float* __restrict__ rel_bias, ushort_t* __restrict__ Ctx)
{
    __shared__ float    tab[2176];             // bias*log2e, rp in [-q0-63, 2047-q0]
    __shared__ ushort_t KV[2][2][2][64 * 64];  // [buf][sub][K/V], 64 KB
    __shared__ float    Lsh[2][64];

    const int tid = threadIdx.x;
    const int w = tid >> 6, lane = tid & 63;
    const int cid32 = lane & 31, hi = lane >> 5;
    const int wk = w & 3, wq = w >> 2;   // wk 0..3 (key-quarter), wq 0..1 (q-half)
    const int mysub = wk >> 1, myhalf = wk & 1;

    // XCD-aware bijective swizzle (512 blocks, 8 XCDs, 64 per XCD = 2 heads)
    const int lin  = blockIdx.x + (blockIdx.y << 5);
    const int wgid = (lin & 7) * 64 + (lin >> 3);
    const int qt = wgid & 31, h = wgid >> 5;
    const int q0 = qt * 64;

    // bias table for rp = k - q in [-q0 - 63, 2047 - q0]
    const int rpmin = -q0 - 63;
    for (int idx = tid; idx < 2175; idx += 512)
        tab[idx] = rel_bias[rel_bucket(rpmin + idx) * NH + h] * LOG2E;

    // Q fragments (B operand of swapped QK^T); Q pre-scaled by log2e in gemm
    const int qg = q0 + wq * 32 + cid32;
    bf16x8 qf[4];
    #pragma unroll
    for (int s = 0; s < 4; s++)
        qf[s] = *(const bf16x8*)&QKV[(size_t)qg * QKV_LD + h * 64 + s * 16 + hi * 8];

    bf16x8 vones;
    {
        union { ushort_t u; __bf16 b; } c; c.u = 0x3F80;  // bf16 1.0
        #pragma unroll
        for (int i = 0; i < 8; i++) vones[i] = c.b;
    }

    f32x16 Oacc[2] = {};   // [dt]: rows q=rowmap(r), col d = dt*32+cid32
    f32x16 Lacc = {};      // rows q=rowmap(r), all cols identical

    const float* tb0 = &tab[myhalf * 32 + 4 * hi + 63 - wq * 32 - cid32];
    const int krow = myhalf * 32 + cid32;   // K row within my sub (A operand)
    const int kxor = krow & 7;

    // per-thread static staging slot: row = tid>>3 (0..63), kg = tid&7
    const int srow = tid >> 3, skg = tid & 7;
    const int sdg = skg ^ (srow & 7);

    auto stage = [&](int buf, int k0) {   // stages keys [k0, k0+128)
        #pragma unroll
        for (int sub = 0; sub < 2; sub++) {
            load_lds16(QKV + (size_t)(k0 + sub * 64 + srow) * QKV_LD + 1024 + h * 64 + sdg * 8,
                       &KV[buf][sub][0][w * 512]);
            load_lds16(Vt + (size_t)(h * 64 + srow) * S_LEN + k0 + sub * 64 + sdg * 8,
                       &KV[buf][sub][1][w * 512]);
        }
    };

    __syncthreads();   // tab ready (also covers qf ordering)
    stage(0, 0);

    int cur = 0;
    #pragma unroll 1
    for (int t = 0; t < 16; ++t) {
        const int k0 = t * 128;
        if (t < 15) {
            stage(cur ^ 1, k0 + 128);                       // prefetch next 128 keys
            asm volatile("s_waitcnt vmcnt(4)" ::: "memory"); // current buf landed
        } else {
            asm volatile("s_waitcnt vmcnt(0)" ::: "memory");
        }
        __builtin_amdgcn_s_barrier();
        __builtin_amdgcn_sched_barrier(0);

        // this wave computes ONLY its 32-key quarter (sub=mysub, half=myhalf)
        const float* tb = tb0 + k0 + mysub * 64;
        f32x16 ST;
        #pragma unroll
        for (int r = 0; r < 16; r++)
            ST[r] = tb[(r & 3) + 8 * (r >> 2)];

        // S^T = K @ Q^T + bias: lane holds col q=cid32, rows key=rowmap(r)+4*hi
        __builtin_amdgcn_s_setprio(1);
        #pragma unroll
        for (int s = 0; s < 4; s++) {
            bf16x8 kf = *(const bf16x8*)&KV[cur][mysub][0][krow * 64 + (((s * 2 + hi) ^ kxor) * 8)];
            ST = __builtin_amdgcn_mfma_f32_32x32x16_bf16(kf, qf[s], ST, 0, 0, 0);
        }
        __builtin_amdgcn_s_setprio(0);

        // p = 2^(S + bias)  (both pre-scaled by log2e); pack key-pairs to bf16
        unsigned u[4][2];
        #pragma unroll
        for (int m = 0; m < 4; m++) {
            u[m][0] = cvtpk(fexp2(ST[4 * m + 0]), fexp2(ST[4 * m + 1]));
            u[m][1] = cvtpk(fexp2(ST[4 * m + 2]), fexp2(ST[4 * m + 3]));
        }

        // per 16-key step: assemble PV A-fragment in-register (2 permlane32_swap)
        #pragma unroll
        for (int s2 = 0; s2 < 2; s2++) {
            unsigned x0 = u[2 * s2][0], x1 = u[2 * s2][1];
            unsigned y0 = u[2 * s2 + 1][0], y1 = u[2 * s2 + 1][1];
            asm("v_permlane32_swap_b32 %0, %1" : "+v"(x0), "+v"(y0));
            asm("v_permlane32_swap_b32 %0, %1" : "+v"(x1), "+v"(y1));
            union { unsigned d[4]; bf16x8 v; } pa;
            pa.d[0] = x0; pa.d[1] = x1; pa.d[2] = y0; pa.d[3] = y1;

            __builtin_amdgcn_s_setprio(1);
            // l += P @ 1
            Lacc = __builtin_amdgcn_mfma_f32_32x32x16_bf16(pa.v, vones, Lacc, 0, 0, 0);
            // O += P @ V
            #pragma unroll
            for (int dt = 0; dt < 2; dt++) {
                int drow = dt * 32 + cid32;
                bf16x8 vf = *(const bf16x8*)&KV[cur][mysub][1][drow * 64 +
                                (((myhalf * 4 + s2 * 2 + hi) ^ (drow & 7)) * 8)];
                Oacc[dt] = __builtin_amdgcn_mfma_f32_32x32x16_bf16(pa.v, vf, Oacc[dt], 0, 0, 0);
            }
            __builtin_amdgcn_s_setprio(0);
        }
        __builtin_amdgcn_s_barrier();   // reads of buf[cur] done before overwrite
        cur ^= 1;
    }

    // ---- 4-way key-quarter combine (tree in LDS), normalize, write Ctx ----
    __syncthreads();
    float* Osh = (float*)&KV[0][0][0][0];   // [2][64][64] f32 = 32 KB, KV dead
    // Phase A: wk 0 and 2 deposit
    if ((wk & 1) == 0) {
        const int buf = wk >> 1;
        #pragma unroll
        for (int dt = 0; dt < 2; dt++)
            #pragma unroll
            for (int r = 0; r < 16; r++) {
                int rloc = (r & 3) + 8 * (r >> 2) + 4 * hi;
                Osh[(buf * 64 + wq * 32 + rloc) * 64 + dt * 32 + cid32] = Oacc[dt][r];
            }
        if (cid32 == 0)
            #pragma unroll
            for (int r = 0; r < 16; r++)
                Lsh[buf][wq * 32 + (r & 3) + 8 * (r >> 2) + 4 * hi] = Lacc[r];
    }
    __syncthreads();
    // Phase B: wk 1 and 3 accumulate
    if ((wk & 1) == 1) {
        const int buf = wk >> 1;
        #pragma unroll
        for (int dt = 0; dt < 2; dt++)
            #pragma unroll
            for (int r = 0; r < 16; r++) {
                int rloc = (r & 3) + 8 * (r >> 2) + 4 * hi;
                Osh[(buf * 64 + wq * 32 + rloc) * 64 + dt * 32 + cid32] += Oacc[dt][r];
            }
        if (cid32 == 0)
            #pragma unroll
            for (int r = 0; r < 16; r++)
                Lsh[buf][wq * 32 + (r & 3) + 8 * (r >> 2) + 4 * hi] += Lacc[r];
    }
    __syncthreads();
    // Phase C: wk==1 waves (both wq) fold the two buffers, normalize, store
    if (wk == 1) {
        #pragma unroll
        for (int r = 0; r < 16; r++) {
            int rloc = (r & 3) + 8 * (r >> 2) + 4 * hi;
            int lrow = wq * 32 + rloc;
            int row = q0 + lrow;
            float inv = 1.f / (Lsh[0][lrow] + Lsh[1][lrow]);
            #pragma unroll
            for (int dt = 0; dt < 2; dt++) {
                float o = (Osh[(0 * 64 + lrow) * 64 + dt * 32 + cid32]
                         + Osh[(1 * 64 + lrow) * 64 + dt * 32 + cid32]) * inv;
                Ctx[(size_t)row * DMODEL + h * 64 + dt * 32 + cid32] = f2bf(o);
            }
        }
    }
}

// ---------------- launch ----------------
extern "C" void kernel_launch(void* const* d_in, const int* in_sizes, int n_in,
                              void* d_out, int out_size, void* d_ws, size_t ws_size,
                              hipStream_t stream) {
    const float* X  = (const float*)d_in[0];
    const float* Wq = (const float*)d_in[1];
    const float* Wk = (const float*)d_in[2];
    const float* Wv = (const float*)d_in[3];
    const float* Wo = (const float*)d_in[4];
    const float* rb = (const float*)d_in[5];
    float* out = (float*)d_out;

    ushort_t* ws = (ushort_t*)d_ws;
    const size_t M1 = 1024 * 1024;
    // Region timeline (ushort units, 14M total = 28 MB):
    //  0..2M   Xb (bf16 X)        -> dead after QKV gemm -> Ctx (attn output)
    //  2..5M   Wt                 -> dead after QKV gemm
    //  5..6M   Wot                (live until final gemm)
    //  6..12M  QKV                (live through attn)
    // 12..14M  Vt                 (live through attn)
    ushort_t* Xb    = ws;
    ushort_t* Wt    = ws + 2 * M1;
    ushort_t* Wot   = ws + 5 * M1;
    ushort_t* QKV   = ws + 6 * M1;
    ushort_t* Vt    = ws + 12 * M1;
    ushort_t* Ctx   = ws;                       // 2M ushort, over dead Xb

    wcast<<<dim3(16, 16, 5), 256, 0, stream>>>(X, Xb, Wq, Wk, Wv, Wo, Wt, Wot);
    gemm_bf16<<<dim3(48, 16), 256, 0, stream>>>(Xb, Wt, QKV, Vt, S_LEN, 3072, DMODEL);
    attn_mfma<<<dim3(32, 16), 512, 0, stream>>>(QKV, Vt, rb, Ctx);
    gemm64_f32<<<dim3(16, 32), 256, 0, stream>>>(Ctx, Wot, out, S_LEN, DMODEL, DMODEL);
}